// Round 9
// baseline (743.286 us; speedup 1.0000x reference)
//
#include <hip/hip_runtime.h>
#include <hip/hip_fp16.h>
#include <math.h>

// FrameletLayer: Chebyshev framelet graph conv + complex linear + CSiLU.
// Scaled recurrence That_k = T_k/32^k (fp16-safe); MFMA f16 complex GEMM.
// CSR via two-level bucket sort; 4B entries {col:16|w:fp16} (N<=65536).
// SpMM: 8 chunk passes of 64B (3.2MB/chunk fits one XCD L2), chunk=blockIdx&7
// XCD pinning (validated by R6 FETCH). 8 rows/wave x 8 lanes/row, serial edge
// loop (2-ahead pipeline). Row-pair degree sort equalizes wave trip counts;
// pairs stay line-adjacent so 64B dst/prev accesses form full 128B lines.
// Feature layout [g][chunk][r][8B-slots]: g=row>>3, r=row&7 -> 4KB per group;
// GEMM block byte ranges align with output rows (in-place T4/T5 in d_out safe).

#define CH   128
#define RPB  128
#define MAXBUCK 512

typedef _Float16 half8 __attribute__((ext_vector_type(8)));
typedef float f32x4 __attribute__((ext_vector_type(4)));

__device__ __forceinline__ uint2 ntload_u2(const uint2* p) {
    unsigned long long v = __builtin_nontemporal_load((const unsigned long long*)p);
    uint2 r; r.x = (unsigned)v; r.y = (unsigned)(v >> 32);
    return r;
}
__device__ __forceinline__ void ntstore_u2(uint2* p, uint2 v) {
    unsigned long long q = (unsigned long long)v.x | ((unsigned long long)v.y << 32);
    __builtin_nontemporal_store(q, (unsigned long long*)p);
}

// feature offset in uint2 units: row i, chunk c, slot s (0..7)
__device__ __forceinline__ size_t foff(int i, int cbase /*= c*64+s*/) {
    return ((size_t)((unsigned)i >> 3) << 9) + (((unsigned)i & 7u) << 3) + cbase;
}

// ---------------- bucket-sort CSR build ----------------

__global__ __launch_bounds__(256) void bucket_hist_k(
        const int* __restrict__ row, int* __restrict__ bucket_cnt, int E, int nbuck) {
    __shared__ int h[MAXBUCK];
    for (int j = threadIdx.x; j < nbuck; j += 256) h[j] = 0;
    __syncthreads();
    int stride = gridDim.x * 256;
    for (int e = blockIdx.x * 256 + threadIdx.x; e < E; e += stride)
        atomicAdd(&h[row[e] >> 7], 1);
    __syncthreads();
    for (int j = threadIdx.x; j < nbuck; j += 256)
        if (h[j]) atomicAdd(&bucket_cnt[j], h[j]);
}

__global__ __launch_bounds__(512) void bucket_scan_k(
        const int* __restrict__ bucket_cnt, int* __restrict__ bucket_start,
        int* __restrict__ bucket_cursor, int nbuck, int E) {
    __shared__ int sd[MAXBUCK];
    int t = threadIdx.x;
    int v = (t < nbuck) ? bucket_cnt[t] : 0;
    sd[t] = v;
    __syncthreads();
    for (int off = 1; off < MAXBUCK; off <<= 1) {
        int y = (t >= off) ? sd[t - off] : 0;
        __syncthreads();
        sd[t] += y;
        __syncthreads();
    }
    int excl = sd[t] - v;
    if (t < nbuck) { bucket_start[t] = excl; bucket_cursor[t] = excl; }
    if (t == 0) bucket_start[nbuck] = E;
}

__global__ __launch_bounds__(256) void bucket_place_k(
        const int* __restrict__ row, const int* __restrict__ col,
        const float* __restrict__ w, int* __restrict__ bucket_cursor,
        uint2* __restrict__ tmp, int E, int chunk, int nbuck) {
    __shared__ int cnt[MAXBUCK];
    __shared__ int cur[MAXBUCK];
    int e0 = blockIdx.x * chunk;
    int e1 = e0 + chunk; if (e1 > E) e1 = E;
    if (e0 >= E) return;
    for (int j = threadIdx.x; j < nbuck; j += 256) cnt[j] = 0;
    __syncthreads();
    for (int e = e0 + threadIdx.x; e < e1; e += 256)
        atomicAdd(&cnt[row[e] >> 7], 1);
    __syncthreads();
    for (int j = threadIdx.x; j < nbuck; j += 256) {
        int c = cnt[j];
        cur[j] = c ? atomicAdd(&bucket_cursor[j], c) : 0;
    }
    __syncthreads();
    for (int e = e0 + threadIdx.x; e < e1; e += 256) {
        int r = row[e];
        int b = r >> 7;
        int p = atomicAdd(&cur[b], 1);
        uint2 ent;
        ent.x = ((unsigned)(r & (RPB - 1)) << 16) | (unsigned)col[e];
        ent.y = __float_as_uint(w[e]);
        tmp[p] = ent;
    }
}

__global__ __launch_bounds__(256) void csr_build_k(
        const uint2* __restrict__ tmp, const int* __restrict__ bucket_start,
        int* __restrict__ row_start, unsigned* __restrict__ csr4,
        int N, int E, int nbuck) {
    __shared__ int hist[RPB];
    __shared__ int sc[RPB];
    __shared__ int curs[RPB];
    int b = blockIdx.x;
    int t = threadIdx.x;
    int base = bucket_start[b];
    int endp = bucket_start[b + 1];
    if (t < RPB) hist[t] = 0;
    __syncthreads();
    for (int e = base + t; e < endp; e += 256)
        atomicAdd(&hist[tmp[e].x >> 16], 1);
    __syncthreads();
    if (t < RPB) sc[t] = hist[t];
    __syncthreads();
    for (int off = 1; off < RPB; off <<= 1) {
        int y = 0;
        if (t < RPB && t >= off) y = sc[t - off];
        __syncthreads();
        if (t < RPB) sc[t] += y;
        __syncthreads();
    }
    int r0 = b << 7;
    if (t < RPB) {
        int excl = sc[t] - hist[t];
        if (r0 + t < N) row_start[r0 + t] = base + excl;
        curs[t] = base + excl;
    }
    if (b == nbuck - 1 && t == 0) row_start[N] = E;
    __syncthreads();
    for (int e = base + t; e < endp; e += 256) {
        uint2 ent = tmp[e];
        int rl = ent.x >> 16;
        unsigned c = ent.x & 0xffffu;
        float wv = __uint_as_float(ent.y) * (-1.0f / 16.0f);   // B/16 entries
        int p = atomicAdd(&curs[rl], 1);
        __half hw = __float2half(wv);
        csr4[p] = (c << 16) | (unsigned)__half_as_ushort(hw);
    }
}

// ---------------- pair-degree counting sort ----------------

__global__ __launch_bounds__(256) void pair_hist_k(
        const int* __restrict__ row_start, int* __restrict__ ph, int NP_) {
    __shared__ int h[256];
    if (threadIdx.x < 256) h[threadIdx.x] = 0;
    __syncthreads();
    int stride = gridDim.x * 256;
    for (int i = blockIdx.x * 256 + threadIdx.x; i < NP_; i += stride) {
        int a = row_start[2*i], b = row_start[2*i+1], c = row_start[2*i+2];
        int d = max(b - a, c - b);
        if (d > 255) d = 255;
        atomicAdd(&h[d], 1);
    }
    __syncthreads();
    if (threadIdx.x < 256 && h[threadIdx.x]) atomicAdd(&ph[threadIdx.x], h[threadIdx.x]);
}

__global__ __launch_bounds__(256) void pair_scan_k(
        const int* __restrict__ ph, int* __restrict__ pcur) {
    __shared__ int sd[256];
    int t = threadIdx.x;
    int v = ph[t];
    sd[t] = v;
    __syncthreads();
    for (int off = 1; off < 256; off <<= 1) {
        int y = (t >= off) ? sd[t - off] : 0;
        __syncthreads();
        sd[t] += y;
        __syncthreads();
    }
    pcur[t] = sd[t] - v;
}

__global__ __launch_bounds__(256) void pair_scatter_k(
        const int* __restrict__ row_start, int* __restrict__ pcur,
        int* __restrict__ sbeg, int* __restrict__ send, int* __restrict__ sorig,
        int NP_) {
    int i = blockIdx.x * 256 + threadIdx.x;
    if (i >= NP_) return;
    int a = row_start[2*i], b = row_start[2*i+1], c = row_start[2*i+2];
    int d = max(b - a, c - b);
    if (d > 255) d = 255;
    int q = atomicAdd(&pcur[d], 1);
    int p = 2 * q;
    sbeg[p]   = a; send[p]   = b; sorig[p]   = 2*i;
    sbeg[p+1] = b; send[p+1] = c; sorig[p+1] = 2*i + 1;
}

// cp[k] = (sum_f theta[f]*approx[f][k]) * 32^k
__global__ void coef_k(const float* __restrict__ approx, const float* __restrict__ theta,
                       float* cp) {
    int k = threadIdx.x;
    if (k < 6 && blockIdx.x == 0) {
        float s = 0.f;
        for (int f = 0; f < 4; f++) s += theta[f] * approx[f * 6 + k];
        float sc = 1.f;
        for (int j = 0; j < k; j++) sc *= 32.f;
        cp[k] = s * sc;
    }
}

// x (fp32) -> fp16 grouped layout. Slot sq in [0,64): halves [4sq,4sq+4);
// h<128 real ch h, else imag ch h-128.
__global__ void convert_x_k(const float4* __restrict__ xr4, const float4* __restrict__ xi4,
                            uint2* __restrict__ xbuf, int N) {
    int idx = blockIdx.x * blockDim.x + threadIdx.x;
    if (idx >= N * 64) return;
    int i = idx >> 6;
    int sq = idx & 63;
    int h = sq * 4;
    int fl = h & 127;
    float4 v = (h < 128) ? xr4[(size_t)i * 32 + (fl >> 2)] : xi4[(size_t)i * 32 + (fl >> 2)];
    __half2 h0 = __floats2half2_rn(v.x, v.y);
    __half2 h1 = __floats2half2_rn(v.z, v.w);
    uint2 pk;
    pk.x = *reinterpret_cast<unsigned*>(&h0);
    pk.y = *reinterpret_cast<unsigned*>(&h1);
    int c = sq >> 3, s = sq & 7;
    xbuf[foff(i, c * 64 + s)] = pk;
}

// WhT[j*256+k] = Wbig[k][j]; Wbig = [[Wr^T, Wi^T],[-Wi^T, Wr^T]]
__global__ void build_whT_k(const float* __restrict__ Wr, const float* __restrict__ Wi,
                            _Float16* __restrict__ WhT) {
    int idx = blockIdx.x * 256 + threadIdx.x;
    int j = idx >> 8, k = idx & 255;
    float v;
    if (j < 128) {
        v = (k < 128) ? Wr[j * 128 + k] : -Wi[j * 128 + (k - 128)];
    } else {
        v = (k < 128) ? Wi[(j - 128) * 128 + k] : Wr[(j - 128) * 128 + (k - 128)];
    }
    WhT[idx] = (_Float16)v;
}

// ---------------- SpMM (chunk-pinned, 8 rows/wave x 8 lanes/row) ----------------

__device__ __forceinline__ void unpack4(uint2 v, float& a, float& b, float& c, float& d) {
    __half2 lo = *reinterpret_cast<__half2*>(&v.x);
    __half2 hi = *reinterpret_cast<__half2*>(&v.y);
    float2 f0 = __half22float2(lo);
    float2 f1 = __half22float2(hi);
    a = f0.x; b = f0.y; c = f1.x; d = f1.y;
}

#define GFMA(ENT)                                                              \
    {                                                                          \
        int col = (int)((ENT) >> 16);                                          \
        float w = __half2float(__ushort_as_half((unsigned short)((ENT) & 0xffffu))); \
        uint2 v = cur[foff(col, cbase)];                                       \
        float a0,a1,a2,a3;                                                     \
        unpack4(v, a0,a1,a2,a3);                                               \
        s0 += w*a0; s1 += w*a1; s2 += w*a2; s3 += w*a3;                        \
    }

// That1 = (B/32) x
__global__ __launch_bounds__(256) void spmm_first8_k(
        const uint2* __restrict__ cur, const unsigned* __restrict__ csr,
        const int* __restrict__ sbeg, const int* __restrict__ send,
        const int* __restrict__ sorig, uint2* __restrict__ dst, int N) {
    int c = blockIdx.x & 7;
    int rb = blockIdx.x >> 3;
    int lane = threadIdx.x & 63, wave = threadIdx.x >> 6;
    int j = lane >> 3, s = lane & 7;
    int p = rb * 32 + wave * 8 + j;
    if (p >= N) return;
    int beg = sbeg[p], end = send[p], orig = sorig[p];
    int cbase = c * 64 + s;
    float s0 = 0.f, s1 = 0.f, s2 = 0.f, s3 = 0.f;
    int e = beg;
    unsigned ea, eb;
    if (e + 2 <= end) { ea = csr[e]; eb = csr[e+1]; }
    for (; e + 4 <= end; e += 2) {
        unsigned na = csr[e+2], nb = csr[e+3];
        GFMA(ea); GFMA(eb);
        ea = na; eb = nb;
    }
    if (e + 2 <= end) { GFMA(ea); GFMA(eb); e += 2; }
    for (; e < end; e++) { unsigned ent = csr[e]; GFMA(ent); }
    s0 *= 0.5f; s1 *= 0.5f; s2 *= 0.5f; s3 *= 0.5f;   // B/16 -> B/32
    __half2 h0 = __floats2half2_rn(s0, s1);
    __half2 h1 = __floats2half2_rn(s2, s3);
    uint2 pk;
    pk.x = *reinterpret_cast<unsigned*>(&h0);
    pk.y = *reinterpret_cast<unsigned*>(&h1);
    ntstore_u2(&dst[foff(orig, cbase)], pk);
}

// That_k = (B/16)*cur - prev/1024
__global__ __launch_bounds__(256) void spmm_step8_k(
        const uint2* __restrict__ cur, const uint2* __restrict__ prev,
        const unsigned* __restrict__ csr,
        const int* __restrict__ sbeg, const int* __restrict__ send,
        const int* __restrict__ sorig, uint2* __restrict__ dst, int N) {
    int c = blockIdx.x & 7;
    int rb = blockIdx.x >> 3;
    int lane = threadIdx.x & 63, wave = threadIdx.x >> 6;
    int j = lane >> 3, s = lane & 7;
    int p = rb * 32 + wave * 8 + j;
    if (p >= N) return;
    int beg = sbeg[p], end = send[p], orig = sorig[p];
    int cbase = c * 64 + s;
    float s0 = 0.f, s1 = 0.f, s2 = 0.f, s3 = 0.f;
    int e = beg;
    unsigned ea, eb;
    if (e + 2 <= end) { ea = csr[e]; eb = csr[e+1]; }
    for (; e + 4 <= end; e += 2) {
        unsigned na = csr[e+2], nb = csr[e+3];
        GFMA(ea); GFMA(eb);
        ea = na; eb = nb;
    }
    if (e + 2 <= end) { GFMA(ea); GFMA(eb); e += 2; }
    for (; e < end; e++) { unsigned ent = csr[e]; GFMA(ent); }
    size_t po = foff(orig, cbase);
    float p0,p1,p2,p3;
    unpack4(ntload_u2(&prev[po]), p0,p1,p2,p3);
    const float inv = 1.0f / 1024.0f;
    float t0 = s0 - inv * p0;
    float t1v = s1 - inv * p1;
    float t2v = s2 - inv * p2;
    float t3v = s3 - inv * p3;
    __half2 h0 = __floats2half2_rn(t0, t1v);
    __half2 h1 = __floats2half2_rn(t2v, t3v);
    uint2 pk;
    pk.x = *reinterpret_cast<unsigned*>(&h0);
    pk.y = *reinterpret_cast<unsigned*>(&h1);
    ntstore_u2(&dst[po], pk);
}

// ---------------- MFMA complex GEMM + SiLU ----------------
// U = (sum_k cp[k]*That_k)/32 staged in f16 from 6 buffers; T4/T5 inside d_out.
// Block reads T4/T5 bytes exactly in its output-row byte range -> in-place safe.
__global__ __launch_bounds__(256) void gemm_silu_mfma_k(
        const _Float16* __restrict__ WhT,
        const uint2* __restrict__ x0, const uint2* __restrict__ t1b,
        const uint2* __restrict__ t2b, const uint2* __restrict__ t3b,
        const float* __restrict__ cp,
        float* __restrict__ out, int N) {
    __shared__ _Float16 U[32][264];
    int t = threadIdx.x;
    int row0 = blockIdx.x * 32;
    const uint2* t4b = (const uint2*)out;
    const uint2* t5b = (const uint2*)out + (size_t)N * 64;
    const float isc = 1.0f / 32.0f;
    float w0 = cp[0], w1 = cp[1], w2 = cp[2], w3 = cp[3], w4 = cp[4], w5 = cp[5];
    for (int q = t; q < 2048; q += 256) {
        int r = q >> 6;
        int sq = q & 63;
        int row = row0 + r;
        float a0 = 0.f, a1 = 0.f, a2 = 0.f, a3 = 0.f;
        if (row < N) {
            size_t idx = foff(row, (sq >> 3) * 64 + (sq & 7));
            float v0,v1,v2,v3;
            unpack4(ntload_u2(&x0[idx]),  v0,v1,v2,v3);
            a0 += w0*v0; a1 += w0*v1; a2 += w0*v2; a3 += w0*v3;
            unpack4(ntload_u2(&t1b[idx]), v0,v1,v2,v3);
            a0 += w1*v0; a1 += w1*v1; a2 += w1*v2; a3 += w1*v3;
            unpack4(ntload_u2(&t2b[idx]), v0,v1,v2,v3);
            a0 += w2*v0; a1 += w2*v1; a2 += w2*v2; a3 += w2*v3;
            unpack4(ntload_u2(&t3b[idx]), v0,v1,v2,v3);
            a0 += w3*v0; a1 += w3*v1; a2 += w3*v2; a3 += w3*v3;
            unpack4(ntload_u2(&t4b[idx]), v0,v1,v2,v3);
            a0 += w4*v0; a1 += w4*v1; a2 += w4*v2; a3 += w4*v3;
            unpack4(ntload_u2(&t5b[idx]), v0,v1,v2,v3);
            a0 += w5*v0; a1 += w5*v1; a2 += w5*v2; a3 += w5*v3;
        }
        int k = sq * 4;
        U[r][k]   = (_Float16)(a0 * isc);
        U[r][k+1] = (_Float16)(a1 * isc);
        U[r][k+2] = (_Float16)(a2 * isc);
        U[r][k+3] = (_Float16)(a3 * isc);
    }
    __syncthreads();

    int wave = t >> 6;
    int lane = t & 63;
    int colbase = wave * 64;
    int lr = lane & 15;
    int lg = lane >> 4;
    f32x4 acc[2][4] = {};
    for (int kb = 0; kb < 8; kb++) {
        int k0 = kb * 32 + lg * 8;
        half8 a0 = *(const half8*)&U[lr][k0];
        half8 a1 = *(const half8*)&U[16 + lr][k0];
        #pragma unroll
        for (int nf = 0; nf < 4; nf++) {
            int col = colbase + nf * 16 + lr;
            half8 b = *(const half8*)&WhT[(size_t)col * 256 + k0];
            acc[0][nf] = __builtin_amdgcn_mfma_f32_16x16x32_f16(a0, b, acc[0][nf], 0, 0, 0);
            acc[1][nf] = __builtin_amdgcn_mfma_f32_16x16x32_f16(a1, b, acc[1][nf], 0, 0, 0);
        }
    }

    #pragma unroll
    for (int mf = 0; mf < 2; mf++) {
        #pragma unroll
        for (int nf = 0; nf < 4; nf++) {
            int col = colbase + nf * 16 + lr;
            int half = col >> 7, jj = col & 127;
            #pragma unroll
            for (int r4 = 0; r4 < 4; r4++) {
                int row = row0 + mf * 16 + lg * 4 + r4;
                if (row < N) {
                    float v = acc[mf][nf][r4] * 32.f;
                    float sv = v / (1.f + expf(-v));
                    out[(size_t)half * N * CH + (size_t)row * CH + jj] = sv;
                }
            }
        }
    }
}

// ---------------- launch ----------------

extern "C" void kernel_launch(void* const* d_in, const int* in_sizes, int n_in,
                              void* d_out, int out_size, void* d_ws, size_t ws_size,
                              hipStream_t stream) {
    const float* xr     = (const float*)d_in[0];
    const float* xi     = (const float*)d_in[1];
    const int*   eidx   = (const int*)d_in[2];
    const float* ew     = (const float*)d_in[3];
    const float* approx = (const float*)d_in[4];
    const float* theta  = (const float*)d_in[5];
    const float* Wr     = (const float*)d_in[6];
    const float* Wi     = (const float*)d_in[7];

    const int N = in_sizes[0] / CH;
    const int E = in_sizes[3];
    const int* rowv = eidx;
    const int* colv = eidx + E;

    float* outp = (float*)d_out;

    char* w8 = (char*)d_ws;
    size_t off = 0;
    auto alloc = [&](size_t bytes) -> void* {
        void* ptr = w8 + off;
        off += (bytes + 255) & ~(size_t)255;
        return ptr;
    };
    float*    cp        = (float*)alloc(64 * 4);
    int*      bucket_cnt= (int*)alloc(MAXBUCK * 4);
    int*      bucket_st = (int*)alloc((MAXBUCK + 1) * 4);
    int*      bucket_cur= (int*)alloc(MAXBUCK * 4);
    int*      ph        = (int*)alloc(256 * 4);
    int*      pcur      = (int*)alloc(256 * 4);
    int*      row_start = (int*)alloc((size_t)(N + 1) * 4);
    int*      sbeg      = (int*)alloc((size_t)N * 4);
    int*      send      = (int*)alloc((size_t)N * 4);
    int*      sorig     = (int*)alloc((size_t)N * 4);
    unsigned* csr4      = (unsigned*)alloc((size_t)E * 4);
    _Float16* WhT       = (_Float16*)alloc(256 * 256 * 2);
    uint2*    xbuf      = (uint2*)alloc((size_t)N * 64 * 8);
    uint2*    T1        = (uint2*)alloc((size_t)N * 64 * 8);
    uint2*    T2        = (uint2*)alloc((size_t)N * 64 * 8);
    uint2*    T3        = (uint2*)alloc((size_t)N * 64 * 8);
    // tmp aliases T3: tmp (E*8B) dead after csr_build_k; T3 first written step3.
    uint2*    tmp       = T3;
    // T4/T5 inside d_out (each exactly N*64 uint2 = one output half).
    uint2*    T4        = (uint2*)d_out;
    uint2*    T5        = (uint2*)d_out + (size_t)N * 64;
    (void)ws_size;

    const int nbuck = (N + RPB - 1) / RPB;
    const int chunk = (E + 255) / 256;
    const int NPairs = N / 2;

    hipMemsetAsync(bucket_cnt, 0, (size_t)MAXBUCK * 4, stream);
    hipMemsetAsync(ph, 0, 256 * 4, stream);
    coef_k<<<1, 64, 0, stream>>>(approx, theta, cp);
    build_whT_k<<<256, 256, 0, stream>>>(Wr, Wi, WhT);
    bucket_hist_k<<<256, 256, 0, stream>>>(rowv, bucket_cnt, E, nbuck);
    bucket_scan_k<<<1, MAXBUCK, 0, stream>>>(bucket_cnt, bucket_st, bucket_cur, nbuck, E);
    bucket_place_k<<<256, 256, 0, stream>>>(rowv, colv, ew, bucket_cur, tmp, E, chunk, nbuck);
    csr_build_k<<<nbuck, 256, 0, stream>>>(tmp, bucket_st, row_start, csr4, N, E, nbuck);
    pair_hist_k<<<128, 256, 0, stream>>>(row_start, ph, NPairs);
    pair_scan_k<<<1, 256, 0, stream>>>(ph, pcur);
    pair_scatter_k<<<(NPairs + 255) / 256, 256, 0, stream>>>(
        row_start, pcur, sbeg, send, sorig, NPairs);
    convert_x_k<<<(N * 64 + 255) / 256, 256, 0, stream>>>(
        (const float4*)xr, (const float4*)xi, xbuf, N);

    // 8 chunk passes x 32 sorted rows/block
    const int NG = 8 * ((N + 31) / 32);

    spmm_first8_k<<<NG, 256, 0, stream>>>(xbuf, csr4, sbeg, send, sorig, T1, N);
    spmm_step8_k<<<NG, 256, 0, stream>>>(T1, xbuf, csr4, sbeg, send, sorig, T2, N);
    spmm_step8_k<<<NG, 256, 0, stream>>>(T2, T1, csr4, sbeg, send, sorig, T3, N);
    spmm_step8_k<<<NG, 256, 0, stream>>>(T3, T2, csr4, sbeg, send, sorig, T4, N);
    spmm_step8_k<<<NG, 256, 0, stream>>>(T4, T3, csr4, sbeg, send, sorig, T5, N);

    gemm_silu_mfma_k<<<(N + 31) / 32, 256, 0, stream>>>(
        WhT, xbuf, T1, T2, T3, cp, outp, N);
}

// Round 10
// 673.327 us; speedup vs baseline: 1.1039x; 1.1039x over previous
//
#include <hip/hip_runtime.h>
#include <hip/hip_fp16.h>
#include <math.h>

// FrameletLayer: Chebyshev framelet graph conv + complex linear + CSiLU.
// Scaled recurrence That_k = T_k/32^k (fp16-safe); MFMA f16 complex GEMM.
// CSR via two-level bucket sort; 4B entries {col:16|w:fp16} (N<=65536).
// SpMM: 8 chunk passes of 64B (3.2MB/chunk fits one XCD L2), chunk=blockIdx&7
// XCD pinning. 8 rows/wave x 8 lanes/row, 4-wide pipelined edge loop (4 gathers
// + 4 CSR loads in flight). Row-pair degree sort equalizes wave trip counts;
// pairs line-adjacent so 64B dst/prev accesses pair into 128B lines. dst uses
// NORMAL stores (dirty lines stay in the XCD-local L2 for the next step's
// gather); prev uses nontemporal loads (one-touch stream).
// Feature layout [g][chunk][r][8B-slots]: g=row>>3, r=row&7 -> 4KB per group.

#define CH   128
#define RPB  128
#define MAXBUCK 512

typedef _Float16 half8 __attribute__((ext_vector_type(8)));
typedef float f32x4 __attribute__((ext_vector_type(4)));

__device__ __forceinline__ uint2 ntload_u2(const uint2* p) {
    unsigned long long v = __builtin_nontemporal_load((const unsigned long long*)p);
    uint2 r; r.x = (unsigned)v; r.y = (unsigned)(v >> 32);
    return r;
}

// feature offset in uint2 units: row i at chunk-slot base cbase (= c*64+s)
__device__ __forceinline__ size_t foff(int i, int cbase) {
    return ((size_t)((unsigned)i >> 3) << 9) + (((unsigned)i & 7u) << 3) + cbase;
}
// row-relative offset (no chunk base): for pre-offset base pointers
__device__ __forceinline__ size_t roff(int i) {
    return ((size_t)((unsigned)i >> 3) << 9) + (((unsigned)i & 7u) << 3);
}

// ---------------- bucket-sort CSR build ----------------

__global__ __launch_bounds__(256) void bucket_hist_k(
        const int* __restrict__ row, int* __restrict__ bucket_cnt, int E, int nbuck) {
    __shared__ int h[MAXBUCK];
    for (int j = threadIdx.x; j < nbuck; j += 256) h[j] = 0;
    __syncthreads();
    int stride = gridDim.x * 256;
    for (int e = blockIdx.x * 256 + threadIdx.x; e < E; e += stride)
        atomicAdd(&h[row[e] >> 7], 1);
    __syncthreads();
    for (int j = threadIdx.x; j < nbuck; j += 256)
        if (h[j]) atomicAdd(&bucket_cnt[j], h[j]);
}

__global__ __launch_bounds__(512) void bucket_scan_k(
        const int* __restrict__ bucket_cnt, int* __restrict__ bucket_start,
        int* __restrict__ bucket_cursor, int nbuck, int E) {
    __shared__ int sd[MAXBUCK];
    int t = threadIdx.x;
    int v = (t < nbuck) ? bucket_cnt[t] : 0;
    sd[t] = v;
    __syncthreads();
    for (int off = 1; off < MAXBUCK; off <<= 1) {
        int y = (t >= off) ? sd[t - off] : 0;
        __syncthreads();
        sd[t] += y;
        __syncthreads();
    }
    int excl = sd[t] - v;
    if (t < nbuck) { bucket_start[t] = excl; bucket_cursor[t] = excl; }
    if (t == 0) bucket_start[nbuck] = E;
}

__global__ __launch_bounds__(256) void bucket_place_k(
        const int* __restrict__ row, const int* __restrict__ col,
        const float* __restrict__ w, int* __restrict__ bucket_cursor,
        uint2* __restrict__ tmp, int E, int chunk, int nbuck) {
    __shared__ int cnt[MAXBUCK];
    __shared__ int cur[MAXBUCK];
    int e0 = blockIdx.x * chunk;
    int e1 = e0 + chunk; if (e1 > E) e1 = E;
    if (e0 >= E) return;
    for (int j = threadIdx.x; j < nbuck; j += 256) cnt[j] = 0;
    __syncthreads();
    for (int e = e0 + threadIdx.x; e < e1; e += 256)
        atomicAdd(&cnt[row[e] >> 7], 1);
    __syncthreads();
    for (int j = threadIdx.x; j < nbuck; j += 256) {
        int c = cnt[j];
        cur[j] = c ? atomicAdd(&bucket_cursor[j], c) : 0;
    }
    __syncthreads();
    for (int e = e0 + threadIdx.x; e < e1; e += 256) {
        int r = row[e];
        int b = r >> 7;
        int p = atomicAdd(&cur[b], 1);
        uint2 ent;
        ent.x = ((unsigned)(r & (RPB - 1)) << 16) | (unsigned)col[e];
        ent.y = __float_as_uint(w[e]);
        tmp[p] = ent;
    }
}

__global__ __launch_bounds__(256) void csr_build_k(
        const uint2* __restrict__ tmp, const int* __restrict__ bucket_start,
        int* __restrict__ row_start, unsigned* __restrict__ csr4,
        int N, int E, int nbuck) {
    __shared__ int hist[RPB];
    __shared__ int sc[RPB];
    __shared__ int curs[RPB];
    int b = blockIdx.x;
    int t = threadIdx.x;
    int base = bucket_start[b];
    int endp = bucket_start[b + 1];
    if (t < RPB) hist[t] = 0;
    __syncthreads();
    for (int e = base + t; e < endp; e += 256)
        atomicAdd(&hist[tmp[e].x >> 16], 1);
    __syncthreads();
    if (t < RPB) sc[t] = hist[t];
    __syncthreads();
    for (int off = 1; off < RPB; off <<= 1) {
        int y = 0;
        if (t < RPB && t >= off) y = sc[t - off];
        __syncthreads();
        if (t < RPB) sc[t] += y;
        __syncthreads();
    }
    int r0 = b << 7;
    if (t < RPB) {
        int excl = sc[t] - hist[t];
        if (r0 + t < N) row_start[r0 + t] = base + excl;
        curs[t] = base + excl;
    }
    if (b == nbuck - 1 && t == 0) row_start[N] = E;
    __syncthreads();
    for (int e = base + t; e < endp; e += 256) {
        uint2 ent = tmp[e];
        int rl = ent.x >> 16;
        unsigned c = ent.x & 0xffffu;
        float wv = __uint_as_float(ent.y) * (-1.0f / 16.0f);   // B/16 entries
        int p = atomicAdd(&curs[rl], 1);
        __half hw = __float2half(wv);
        csr4[p] = (c << 16) | (unsigned)__half_as_ushort(hw);
    }
}

// ---------------- pair-degree counting sort ----------------

__global__ __launch_bounds__(256) void pair_hist_k(
        const int* __restrict__ row_start, int* __restrict__ ph, int NP_) {
    __shared__ int h[256];
    if (threadIdx.x < 256) h[threadIdx.x] = 0;
    __syncthreads();
    int stride = gridDim.x * 256;
    for (int i = blockIdx.x * 256 + threadIdx.x; i < NP_; i += stride) {
        int a = row_start[2*i], b = row_start[2*i+1], c = row_start[2*i+2];
        int d = max(b - a, c - b);
        if (d > 255) d = 255;
        atomicAdd(&h[d], 1);
    }
    __syncthreads();
    if (threadIdx.x < 256 && h[threadIdx.x]) atomicAdd(&ph[threadIdx.x], h[threadIdx.x]);
}

__global__ __launch_bounds__(256) void pair_scan_k(
        const int* __restrict__ ph, int* __restrict__ pcur) {
    __shared__ int sd[256];
    int t = threadIdx.x;
    int v = ph[t];
    sd[t] = v;
    __syncthreads();
    for (int off = 1; off < 256; off <<= 1) {
        int y = (t >= off) ? sd[t - off] : 0;
        __syncthreads();
        sd[t] += y;
        __syncthreads();
    }
    pcur[t] = sd[t] - v;
}

__global__ __launch_bounds__(256) void pair_scatter_k(
        const int* __restrict__ row_start, int* __restrict__ pcur,
        int* __restrict__ sbeg, int* __restrict__ send, int* __restrict__ sorig,
        int NP_) {
    int i = blockIdx.x * 256 + threadIdx.x;
    if (i >= NP_) return;
    int a = row_start[2*i], b = row_start[2*i+1], c = row_start[2*i+2];
    int d = max(b - a, c - b);
    if (d > 255) d = 255;
    int q = atomicAdd(&pcur[d], 1);
    int p = 2 * q;
    sbeg[p]   = a; send[p]   = b; sorig[p]   = 2*i;
    sbeg[p+1] = b; send[p+1] = c; sorig[p+1] = 2*i + 1;
}

// cp[k] = (sum_f theta[f]*approx[f][k]) * 32^k
__global__ void coef_k(const float* __restrict__ approx, const float* __restrict__ theta,
                       float* cp) {
    int k = threadIdx.x;
    if (k < 6 && blockIdx.x == 0) {
        float s = 0.f;
        for (int f = 0; f < 4; f++) s += theta[f] * approx[f * 6 + k];
        float sc = 1.f;
        for (int j = 0; j < k; j++) sc *= 32.f;
        cp[k] = s * sc;
    }
}

// x (fp32) -> fp16 grouped layout. Slot sq in [0,64): halves [4sq,4sq+4);
// h<128 real ch h, else imag ch h-128.
__global__ void convert_x_k(const float4* __restrict__ xr4, const float4* __restrict__ xi4,
                            uint2* __restrict__ xbuf, int N) {
    int idx = blockIdx.x * blockDim.x + threadIdx.x;
    if (idx >= N * 64) return;
    int i = idx >> 6;
    int sq = idx & 63;
    int h = sq * 4;
    int fl = h & 127;
    float4 v = (h < 128) ? xr4[(size_t)i * 32 + (fl >> 2)] : xi4[(size_t)i * 32 + (fl >> 2)];
    __half2 h0 = __floats2half2_rn(v.x, v.y);
    __half2 h1 = __floats2half2_rn(v.z, v.w);
    uint2 pk;
    pk.x = *reinterpret_cast<unsigned*>(&h0);
    pk.y = *reinterpret_cast<unsigned*>(&h1);
    int c = sq >> 3, s = sq & 7;
    xbuf[foff(i, c * 64 + s)] = pk;
}

// WhT[j*256+k] = Wbig[k][j]; Wbig = [[Wr^T, Wi^T],[-Wi^T, Wr^T]]
__global__ void build_whT_k(const float* __restrict__ Wr, const float* __restrict__ Wi,
                            _Float16* __restrict__ WhT) {
    int idx = blockIdx.x * 256 + threadIdx.x;
    int j = idx >> 8, k = idx & 255;
    float v;
    if (j < 128) {
        v = (k < 128) ? Wr[j * 128 + k] : -Wi[j * 128 + (k - 128)];
    } else {
        v = (k < 128) ? Wi[(j - 128) * 128 + k] : Wr[(j - 128) * 128 + (k - 128)];
    }
    WhT[idx] = (_Float16)v;
}

// ---------------- SpMM (chunk-pinned, 8 rows/wave x 8 lanes/row) ----------------

__device__ __forceinline__ void unpack4(uint2 v, float& a, float& b, float& c, float& d) {
    __half2 lo = *reinterpret_cast<__half2*>(&v.x);
    __half2 hi = *reinterpret_cast<__half2*>(&v.y);
    float2 f0 = __half22float2(lo);
    float2 f1 = __half22float2(hi);
    a = f0.x; b = f0.y; c = f1.x; d = f1.y;
}

#define GFMA(ENT)                                                              \
    {                                                                          \
        int col = (int)((ENT) >> 16);                                          \
        float w = __half2float(__ushort_as_half((unsigned short)((ENT) & 0xffffu))); \
        uint2 v = curc[roff(col)];                                             \
        float a0,a1,a2,a3;                                                     \
        unpack4(v, a0,a1,a2,a3);                                               \
        s0 += w*a0; s1 += w*a1; s2 += w*a2; s3 += w*a3;                        \
    }

// 4-wide pipelined gather: 4 gathers + 4 CSR loads in flight per lane
#define GATHER_LOOP                                                            \
    int e = beg;                                                               \
    unsigned e0, e1, e2, e3;                                                   \
    if (e + 4 <= end) { e0 = csr[e]; e1 = csr[e+1]; e2 = csr[e+2]; e3 = csr[e+3]; } \
    for (; e + 8 <= end; e += 4) {                                             \
        unsigned n0 = csr[e+4], n1 = csr[e+5], n2 = csr[e+6], n3 = csr[e+7];   \
        GFMA(e0); GFMA(e1); GFMA(e2); GFMA(e3);                                \
        e0 = n0; e1 = n1; e2 = n2; e3 = n3;                                    \
    }                                                                          \
    if (e + 4 <= end) { GFMA(e0); GFMA(e1); GFMA(e2); GFMA(e3); e += 4; }      \
    for (; e < end; e++) { unsigned ent = csr[e]; GFMA(ent); }

// That1 = (B/32) x
__global__ __launch_bounds__(256) void spmm_first8_k(
        const uint2* __restrict__ cur, const unsigned* __restrict__ csr,
        const int* __restrict__ sbeg, const int* __restrict__ send,
        const int* __restrict__ sorig, uint2* __restrict__ dst, int N) {
    int c = blockIdx.x & 7;
    int rb = blockIdx.x >> 3;
    int lane = threadIdx.x & 63, wave = threadIdx.x >> 6;
    int j = lane >> 3, s = lane & 7;
    int p = rb * 32 + wave * 8 + j;
    if (p >= N) return;
    int beg = sbeg[p], end = send[p], orig = sorig[p];
    int cbase = c * 64 + s;
    const uint2* curc = cur + cbase;
    float s0 = 0.f, s1 = 0.f, s2 = 0.f, s3 = 0.f;
    GATHER_LOOP
    s0 *= 0.5f; s1 *= 0.5f; s2 *= 0.5f; s3 *= 0.5f;   // B/16 -> B/32
    __half2 h0 = __floats2half2_rn(s0, s1);
    __half2 h1 = __floats2half2_rn(s2, s3);
    uint2 pk;
    pk.x = *reinterpret_cast<unsigned*>(&h0);
    pk.y = *reinterpret_cast<unsigned*>(&h1);
    dst[foff(orig, cbase)] = pk;
}

// That_k = (B/16)*cur - prev/1024
__global__ __launch_bounds__(256) void spmm_step8_k(
        const uint2* __restrict__ cur, const uint2* __restrict__ prev,
        const unsigned* __restrict__ csr,
        const int* __restrict__ sbeg, const int* __restrict__ send,
        const int* __restrict__ sorig, uint2* __restrict__ dst, int N) {
    int c = blockIdx.x & 7;
    int rb = blockIdx.x >> 3;
    int lane = threadIdx.x & 63, wave = threadIdx.x >> 6;
    int j = lane >> 3, s = lane & 7;
    int p = rb * 32 + wave * 8 + j;
    if (p >= N) return;
    int beg = sbeg[p], end = send[p], orig = sorig[p];
    int cbase = c * 64 + s;
    const uint2* curc = cur + cbase;
    float s0 = 0.f, s1 = 0.f, s2 = 0.f, s3 = 0.f;
    GATHER_LOOP
    size_t po = foff(orig, cbase);
    float p0,p1,p2,p3;
    unpack4(ntload_u2(&prev[po]), p0,p1,p2,p3);
    const float inv = 1.0f / 1024.0f;
    float t0 = s0 - inv * p0;
    float t1v = s1 - inv * p1;
    float t2v = s2 - inv * p2;
    float t3v = s3 - inv * p3;
    __half2 h0 = __floats2half2_rn(t0, t1v);
    __half2 h1 = __floats2half2_rn(t2v, t3v);
    uint2 pk;
    pk.x = *reinterpret_cast<unsigned*>(&h0);
    pk.y = *reinterpret_cast<unsigned*>(&h1);
    dst[po] = pk;
}

// ---------------- MFMA complex GEMM + SiLU ----------------
// U = (sum_k cp[k]*That_k)/32 staged in f16 from 6 buffers; T4/T5 inside d_out.
// Block reads T4/T5 bytes exactly in its output-row byte range -> in-place safe.
__global__ __launch_bounds__(256) void gemm_silu_mfma_k(
        const _Float16* __restrict__ WhT,
        const uint2* __restrict__ x0, const uint2* __restrict__ t1b,
        const uint2* __restrict__ t2b, const uint2* __restrict__ t3b,
        const float* __restrict__ cp,
        float* __restrict__ out, int N) {
    __shared__ _Float16 U[32][264];
    int t = threadIdx.x;
    int row0 = blockIdx.x * 32;
    const uint2* t4b = (const uint2*)out;
    const uint2* t5b = (const uint2*)out + (size_t)N * 64;
    const float isc = 1.0f / 32.0f;
    float w0 = cp[0], w1 = cp[1], w2 = cp[2], w3 = cp[3], w4 = cp[4], w5 = cp[5];
    for (int q = t; q < 2048; q += 256) {
        int r = q >> 6;
        int sq = q & 63;
        int row = row0 + r;
        float a0 = 0.f, a1 = 0.f, a2 = 0.f, a3 = 0.f;
        if (row < N) {
            size_t idx = foff(row, (sq >> 3) * 64 + (sq & 7));
            float v0,v1,v2,v3;
            unpack4(ntload_u2(&x0[idx]),  v0,v1,v2,v3);
            a0 += w0*v0; a1 += w0*v1; a2 += w0*v2; a3 += w0*v3;
            unpack4(ntload_u2(&t1b[idx]), v0,v1,v2,v3);
            a0 += w1*v0; a1 += w1*v1; a2 += w1*v2; a3 += w1*v3;
            unpack4(ntload_u2(&t2b[idx]), v0,v1,v2,v3);
            a0 += w2*v0; a1 += w2*v1; a2 += w2*v2; a3 += w2*v3;
            unpack4(ntload_u2(&t3b[idx]), v0,v1,v2,v3);
            a0 += w3*v0; a1 += w3*v1; a2 += w3*v2; a3 += w3*v3;
            unpack4(ntload_u2(&t4b[idx]), v0,v1,v2,v3);
            a0 += w4*v0; a1 += w4*v1; a2 += w4*v2; a3 += w4*v3;
            unpack4(ntload_u2(&t5b[idx]), v0,v1,v2,v3);
            a0 += w5*v0; a1 += w5*v1; a2 += w5*v2; a3 += w5*v3;
        }
        int k = sq * 4;
        U[r][k]   = (_Float16)(a0 * isc);
        U[r][k+1] = (_Float16)(a1 * isc);
        U[r][k+2] = (_Float16)(a2 * isc);
        U[r][k+3] = (_Float16)(a3 * isc);
    }
    __syncthreads();

    int wave = t >> 6;
    int lane = t & 63;
    int colbase = wave * 64;
    int lr = lane & 15;
    int lg = lane >> 4;
    f32x4 acc[2][4] = {};
    for (int kb = 0; kb < 8; kb++) {
        int k0 = kb * 32 + lg * 8;
        half8 a0 = *(const half8*)&U[lr][k0];
        half8 a1 = *(const half8*)&U[16 + lr][k0];
        #pragma unroll
        for (int nf = 0; nf < 4; nf++) {
            int col = colbase + nf * 16 + lr;
            half8 b = *(const half8*)&WhT[(size_t)col * 256 + k0];
            acc[0][nf] = __builtin_amdgcn_mfma_f32_16x16x32_f16(a0, b, acc[0][nf], 0, 0, 0);
            acc[1][nf] = __builtin_amdgcn_mfma_f32_16x16x32_f16(a1, b, acc[1][nf], 0, 0, 0);
        }
    }

    #pragma unroll
    for (int mf = 0; mf < 2; mf++) {
        #pragma unroll
        for (int nf = 0; nf < 4; nf++) {
            int col = colbase + nf * 16 + lr;
            int half = col >> 7, jj = col & 127;
            #pragma unroll
            for (int r4 = 0; r4 < 4; r4++) {
                int row = row0 + mf * 16 + lg * 4 + r4;
                if (row < N) {
                    float v = acc[mf][nf][r4] * 32.f;
                    float sv = v / (1.f + expf(-v));
                    out[(size_t)half * N * CH + (size_t)row * CH + jj] = sv;
                }
            }
        }
    }
}

// ---------------- launch ----------------

extern "C" void kernel_launch(void* const* d_in, const int* in_sizes, int n_in,
                              void* d_out, int out_size, void* d_ws, size_t ws_size,
                              hipStream_t stream) {
    const float* xr     = (const float*)d_in[0];
    const float* xi     = (const float*)d_in[1];
    const int*   eidx   = (const int*)d_in[2];
    const float* ew     = (const float*)d_in[3];
    const float* approx = (const float*)d_in[4];
    const float* theta  = (const float*)d_in[5];
    const float* Wr     = (const float*)d_in[6];
    const float* Wi     = (const float*)d_in[7];

    const int N = in_sizes[0] / CH;
    const int E = in_sizes[3];
    const int* rowv = eidx;
    const int* colv = eidx + E;

    float* outp = (float*)d_out;

    char* w8 = (char*)d_ws;
    size_t off = 0;
    auto alloc = [&](size_t bytes) -> void* {
        void* ptr = w8 + off;
        off += (bytes + 255) & ~(size_t)255;
        return ptr;
    };
    float*    cp        = (float*)alloc(64 * 4);
    int*      bucket_cnt= (int*)alloc(MAXBUCK * 4);
    int*      bucket_st = (int*)alloc((MAXBUCK + 1) * 4);
    int*      bucket_cur= (int*)alloc(MAXBUCK * 4);
    int*      ph        = (int*)alloc(256 * 4);
    int*      pcur      = (int*)alloc(256 * 4);
    int*      row_start = (int*)alloc((size_t)(N + 1) * 4);
    int*      sbeg      = (int*)alloc((size_t)N * 4);
    int*      send      = (int*)alloc((size_t)N * 4);
    int*      sorig     = (int*)alloc((size_t)N * 4);
    unsigned* csr4      = (unsigned*)alloc((size_t)E * 4);
    _Float16* WhT       = (_Float16*)alloc(256 * 256 * 2);
    uint2*    xbuf      = (uint2*)alloc((size_t)N * 64 * 8);
    uint2*    T1        = (uint2*)alloc((size_t)N * 64 * 8);
    uint2*    T2        = (uint2*)alloc((size_t)N * 64 * 8);
    uint2*    T3        = (uint2*)alloc((size_t)N * 64 * 8);
    // tmp aliases T3: tmp (E*8B) dead after csr_build_k; T3 first written step3.
    uint2*    tmp       = T3;
    // T4/T5 inside d_out (each exactly N*64 uint2 = one output half).
    uint2*    T4        = (uint2*)d_out;
    uint2*    T5        = (uint2*)d_out + (size_t)N * 64;
    (void)ws_size;

    const int nbuck = (N + RPB - 1) / RPB;
    const int chunk = (E + 255) / 256;
    const int NPairs = N / 2;

    hipMemsetAsync(bucket_cnt, 0, (size_t)MAXBUCK * 4, stream);
    hipMemsetAsync(ph, 0, 256 * 4, stream);
    coef_k<<<1, 64, 0, stream>>>(approx, theta, cp);
    build_whT_k<<<256, 256, 0, stream>>>(Wr, Wi, WhT);
    bucket_hist_k<<<256, 256, 0, stream>>>(rowv, bucket_cnt, E, nbuck);
    bucket_scan_k<<<1, MAXBUCK, 0, stream>>>(bucket_cnt, bucket_st, bucket_cur, nbuck, E);
    bucket_place_k<<<256, 256, 0, stream>>>(rowv, colv, ew, bucket_cur, tmp, E, chunk, nbuck);
    csr_build_k<<<nbuck, 256, 0, stream>>>(tmp, bucket_st, row_start, csr4, N, E, nbuck);
    pair_hist_k<<<128, 256, 0, stream>>>(row_start, ph, NPairs);
    pair_scan_k<<<1, 256, 0, stream>>>(ph, pcur);
    pair_scatter_k<<<(NPairs + 255) / 256, 256, 0, stream>>>(
        row_start, pcur, sbeg, send, sorig, NPairs);
    convert_x_k<<<(N * 64 + 255) / 256, 256, 0, stream>>>(
        (const float4*)xr, (const float4*)xi, xbuf, N);

    // 8 chunk passes x 32 sorted rows/block
    const int NG = 8 * ((N + 31) / 32);

    spmm_first8_k<<<NG, 256, 0, stream>>>(xbuf, csr4, sbeg, send, sorig, T1, N);
    spmm_step8_k<<<NG, 256, 0, stream>>>(T1, xbuf, csr4, sbeg, send, sorig, T2, N);
    spmm_step8_k<<<NG, 256, 0, stream>>>(T2, T1, csr4, sbeg, send, sorig, T3, N);
    spmm_step8_k<<<NG, 256, 0, stream>>>(T3, T2, csr4, sbeg, send, sorig, T4, N);
    spmm_step8_k<<<NG, 256, 0, stream>>>(T4, T3, csr4, sbeg, send, sorig, T5, N);

    gemm_silu_mfma_k<<<(N + 31) / 32, 256, 0, stream>>>(
        WhT, xbuf, T1, T2, T3, cp, outp, N);
}